// Round 4
// baseline (71.509 us; speedup 1.0000x reference)
//
#include <hip/hip_runtime.h>

// ConvCaps: b=16, A=32, B=32, K=3, P=4, stride=2, h=w=14 -> oh=ow=6
#define AA 32
#define BB 32
#define CC 16
#define KKA 288
#define OHW 6
#define LL 36
#define NBL 576
#define HH 14
#define WWD 14

// ---- workspace layout ----
// ushort region (from byte 0):
#define W1B_OFF   0ull          // bf16 [288][512][16] = 2,359,296
#define W2B_OFF   2359296ull    // bf16 [288][32][16]  =   147,456
#define PU16_OFF  2506752ull    // bf16 [576][288][16] = 2,654,208
#define AR16_OFF  5160960ull    // bf16 [576][288][32] = 5,308,416
// float region starts at byte 20,938,752:
#define FREG_BYTE 20938752ull
#define AU_F      0ull          // f32 [576][288]      = 165,888
#define ARSUMP_F  165888ull     // f32 [18][576][32]   = 331,776
#define ARSUM_F   497664ull     // f32 [576][32]       =  18,432
#define PREP_F    516096ull     // f32 [2][512][576]   = 589,824

typedef __attribute__((ext_vector_type(8))) short bf16x8;
typedef __attribute__((ext_vector_type(4))) float f32x4;

__device__ __forceinline__ unsigned cvtpk(float lo, float hi) {
    unsigned r;
    asm("v_cvt_pk_bf16_f32 %0, %1, %2" : "=v"(r) : "v"(lo), "v"(hi));
    return r;
}
__device__ __forceinline__ float blo(unsigned u) {
    return __builtin_bit_cast(float, u << 16);
}
__device__ __forceinline__ float bhi(unsigned u) {
    return __builtin_bit_cast(float, u & 0xffff0000u);
}

// ---------------------------------------------------------------------------
// Kernel 0: fused weight-cvt (blocks 0..1223) + patch gather (blocks 1224..1735)
// ---------------------------------------------------------------------------
__global__ __launch_bounds__(256) void k_prep(
    const float* __restrict__ W1, const float* __restrict__ W2,
    const float* __restrict__ a, const float* __restrict__ pose,
    unsigned short* __restrict__ W1b, unsigned short* __restrict__ W2b,
    unsigned short* __restrict__ pu16, float* __restrict__ auf)
{
    __shared__ float ps[16][196];
    __shared__ float as_[196];
    const int tid = threadIdx.x;

    if (blockIdx.x < 1224) {
        size_t i = ((size_t)blockIdx.x * 256 + tid) * 8;
        const float* src;
        unsigned short* dst;
        if (i < 2359296ull) { src = W1 + i; dst = W1b + i; }
        else { src = W2 + (i - 2359296ull); dst = W2b + (i - 2359296ull); }
        float4 v0 = *reinterpret_cast<const float4*>(src);
        float4 v1 = *reinterpret_cast<const float4*>(src + 4);
        uint4 o;
        o.x = cvtpk(v0.x, v0.y);
        o.y = cvtpk(v0.z, v0.w);
        o.z = cvtpk(v1.x, v1.y);
        o.w = cvtpk(v1.z, v1.w);
        *reinterpret_cast<uint4*>(dst) = o;
        return;
    }

    const int bid = blockIdx.x - 1224;
    const int b = bid >> 5, aidx = bid & 31;

    const float* psrc = pose + ((size_t)b * 512 + (size_t)aidx * 16) * 196;
    for (int t = tid; t < 3136; t += 256) ((float*)ps)[t] = psrc[t];
    const float* asrc = a + ((size_t)b * 32 + aidx) * 196;
    if (tid < 196) as_[tid] = asrc[tid];
    __syncthreads();

    for (int t = tid; t < 2592; t += 256) {
        int c2 = t & 7;
        int kk = (t >> 3) % 9;
        int l  = t / 72;
        int oy = l / 6, ox = l - (l / 6) * 6;
        int ki = kk / 3, kj = kk - (kk / 3) * 3;
        int pix = (oy * 2 + ki) * 14 + ox * 2 + kj;
        unsigned v = cvtpk(ps[c2 * 2][pix], ps[c2 * 2 + 1][pix]);
        *reinterpret_cast<unsigned*>(
            pu16 + (((size_t)(b * 36 + l)) * KKA + kk * 32 + aidx) * 16 + c2 * 2) = v;
    }
    for (int t = tid; t < 324; t += 256) {
        int kk = t % 9, l = t / 9;
        int oy = l / 6, ox = l - (l / 6) * 6;
        int ki = kk / 3, kj = kk - (kk / 3) * 3;
        auf[((size_t)(b * 36 + l)) * KKA + kk * 32 + aidx] =
            as_[(oy * 2 + ki) * 14 + ox * 2 + kj];
    }
}

// ---------------------------------------------------------------------------
// Kernel 1: logits via zero-padded 16x16x32 MFMA + softmax (no max-sub:
// |logit| <= ~3 analytically, exp-safe; softmax is shift-invariant).
// Grid (36 bl-tiles, 18 n-ranges of 16); 4 waves each own 4 n.
// Writes ar16[bl][n][j] (bf16, = a_u * softmax) and arsump[18][576][32].
// ---------------------------------------------------------------------------
__global__ __launch_bounds__(256) void k_logit(
    const unsigned short* __restrict__ W2b, const unsigned short* __restrict__ pu16,
    const float* __restrict__ b2, const float* __restrict__ auf,
    unsigned short* __restrict__ ar16, float* __restrict__ arsump)
{
    __shared__ float b2_s[16][32];     // 2 KB
    __shared__ float au_s[16][17];     // 1.1 KB
    __shared__ float asum_s[4][16][32]; // 8 KB
    const int bl0 = blockIdx.x * 16;
    const int n0b = blockIdx.y * 16;
    const int tid = threadIdx.x;

    #pragma unroll
    for (int k = 0; k < 2; ++k) {
        int t = tid + k * 256;
        b2_s[t >> 5][t & 31] = b2[(size_t)(n0b + (t >> 5)) * 32 + (t & 31)];
    }
    {
        int blr = tid >> 4, nl = tid & 15;
        au_s[blr][nl] = auf[((size_t)(bl0 + blr)) * KKA + n0b + nl];
    }
    __syncthreads();

    const int w = tid >> 6, lane = tid & 63;
    const int g = lane >> 4, d = lane & 15;
    float asum[8] = {0.f, 0.f, 0.f, 0.f, 0.f, 0.f, 0.f, 0.f};

    #pragma unroll
    for (int nn = 0; nn < 4; ++nn) {
        const int nl = w * 4 + nn;
        const int n  = n0b + nl;
        uint4 a0 = {0, 0, 0, 0}, a1 = {0, 0, 0, 0}, bbv = {0, 0, 0, 0};
        if (g < 2) {
            a0 = *reinterpret_cast<const uint4*>(W2b + ((size_t)n * 32 + d) * 16 + g * 8);
            a1 = *reinterpret_cast<const uint4*>(W2b + ((size_t)n * 32 + 16 + d) * 16 + g * 8);
            bbv = *reinterpret_cast<const uint4*>(
                pu16 + (((size_t)(bl0 + d)) * KKA + n) * 16 + g * 8);
        }
        f32x4 zero = {0.f, 0.f, 0.f, 0.f};
        f32x4 c0 = __builtin_amdgcn_mfma_f32_16x16x32_bf16(
            __builtin_bit_cast(bf16x8, a0), __builtin_bit_cast(bf16x8, bbv), zero, 0, 0, 0);
        f32x4 c1 = __builtin_amdgcn_mfma_f32_16x16x32_bf16(
            __builtin_bit_cast(bf16x8, a1), __builtin_bit_cast(bf16x8, bbv), zero, 0, 0, 0);

        float v[8];
        float s = 0.f;
        #pragma unroll
        for (int i = 0; i < 4; ++i) {
            v[i]     = __expf(c0[i] + b2_s[nl][g * 4 + i]);
            v[4 + i] = __expf(c1[i] + b2_s[nl][16 + g * 4 + i]);
            s += v[i] + v[4 + i];
        }
        s += __shfl_xor(s, 16);
        s += __shfl_xor(s, 32);
        const float scale = au_s[d][nl] / s;
        float p[8];
        #pragma unroll
        for (int i = 0; i < 8; ++i) { p[i] = v[i] * scale; asum[i] += p[i]; }

        unsigned short* dst = ar16 + (((size_t)(bl0 + d)) * KKA + n) * 32;
        uint2 u0, u1;
        u0.x = cvtpk(p[0], p[1]); u0.y = cvtpk(p[2], p[3]);
        u1.x = cvtpk(p[4], p[5]); u1.y = cvtpk(p[6], p[7]);
        *reinterpret_cast<uint2*>(dst + g * 4) = u0;
        *reinterpret_cast<uint2*>(dst + 16 + g * 4) = u1;
    }
    // cross-wave reduce of asum -> one partial row per block
    #pragma unroll
    for (int i = 0; i < 4; ++i) {
        asum_s[w][d][g * 4 + i]      = asum[i];
        asum_s[w][d][16 + g * 4 + i] = asum[4 + i];
    }
    __syncthreads();
    #pragma unroll
    for (int k = 0; k < 2; ++k) {
        int idx = tid + k * 256;
        int dd = idx >> 5, j = idx & 31;
        float s = asum_s[0][dd][j] + asum_s[1][dd][j] + asum_s[2][dd][j] + asum_s[3][dd][j];
        arsump[(size_t)blockIdx.y * 18432 + ((size_t)(bl0 + dd)) * 32 + j] = s;
    }
}

// ---------------------------------------------------------------------------
// Kernel 2: finish routing — arsum = sum of 18 partials; a_out = arsum/au_tot.
// ---------------------------------------------------------------------------
__global__ __launch_bounds__(256) void k_finish(
    const float* __restrict__ arsump, const float* __restrict__ auf,
    float* __restrict__ arsum, float* __restrict__ out_a)
{
    const int tid = threadIdx.x;
    const int wid = tid >> 6, lane = tid & 63;
    const int bl = blockIdx.x * 4 + wid;
    const int j = lane & 31, h = lane >> 5;

    float s = 0.f;
    #pragma unroll
    for (int k = 0; k < 9; ++k) {
        int r = h * 9 + k;
        s += arsump[(size_t)r * 18432 + (size_t)bl * 32 + j];
    }
    s += __shfl_xor(s, 32);

    float at = 0.f;
    #pragma unroll
    for (int k = 0; k < 5; ++k) {
        int n = k * 64 + lane;
        if (n < KKA) at += auf[(size_t)bl * KKA + n];
    }
    #pragma unroll
    for (int m = 1; m <= 32; m <<= 1) at += __shfl_xor(at, m);

    if (lane < 32) {
        arsum[(size_t)bl * 32 + j] = s;
        int b = bl / 36, l = bl - (bl / 36) * 36;
        out_a[((size_t)b * 32 + j) * 36 + l] = s / at;
    }
}

// ---------------------------------------------------------------------------
// Kernel 3: MFMA pose contraction, 32-bl tile (A-frag reuse x2), K-split.
// Grid (18 bl-tiles, 16 j-pairs, 2 K-halves); 4 waves = 2 j x 2 n-sub-halves.
// ---------------------------------------------------------------------------
__global__ __launch_bounds__(256) void k_pose(
    const unsigned short* __restrict__ W1b, const unsigned short* __restrict__ pu16,
    const unsigned short* __restrict__ ar16, const float* __restrict__ arsum,
    float* __restrict__ prep)
{
    __shared__ unsigned long long pu_s8[2][2][16][32];  // [h][u][bl16][8n*16c] 16 KB
    __shared__ unsigned arn_s[2][16][145];              // [u][bl][nl] 18.6 KB
    __shared__ float red_s[2][2][256];                  // 8 KB

    const int bl0 = blockIdx.x * 32;
    const int jp  = blockIdx.y;
    const int z   = blockIdx.z;
    const int tid = threadIdx.x;
    const int w = tid >> 6, lane = tid & 63;
    const int jl = w >> 1, h = w & 1;
    const int g = lane >> 4, d = lane & 15;
    const int jg = jp * 2 + jl;
    const int gh = g >> 1, co = (g & 1) * 8;

    for (int t = tid; t < 4608; t += 256) {
        int blr = t / 144, nl = t - blr * 144;
        arn_s[blr >> 4][blr & 15][nl] = *reinterpret_cast<const unsigned*>(
            ar16 + (((size_t)(bl0 + blr)) * KKA + z * 144 + nl) * 32 + jp * 2);
    }

    f32x4 acc[2][2] = {{{0.f,0.f,0.f,0.f},{0.f,0.f,0.f,0.f}},
                       {{0.f,0.f,0.f,0.f},{0.f,0.f,0.f,0.f}}};

    for (int ci = 0; ci < 9; ++ci) {
        __syncthreads();
        // stage pu: 2 h x 2 u x 16 bl x 8 n x 16 c bf16 = 16 KB (8 uint2/thread)
        #pragma unroll
        for (int k = 0; k < 8; ++k) {
            int idx = tid + k * 256;
            int hh = idx >> 10, r = idx & 1023;
            int u = r >> 9, rr = r & 511;
            int nl8 = rr >> 6, blr = (rr >> 2) & 15, q4 = rr & 3;
            uint2 v = *reinterpret_cast<const uint2*>(
                pu16 + (((size_t)(bl0 + u * 16 + blr)) * KKA
                        + z * 144 + hh * 72 + ci * 8 + nl8) * 16 + q4 * 4);
            pu_s8[hh][u][blr][(nl8 * 4 + q4) ^ ((blr & 7) << 1)] =
                __builtin_bit_cast(unsigned long long, v);
        }
        __syncthreads();
        #pragma unroll
        for (int sp = 0; sp < 4; ++sp) {
            const int nl = h * 72 + ci * 8 + sp * 2 + gh;
            const int n  = z * 144 + nl;
            uint4 a4 = *reinterpret_cast<const uint4*>(
                W1b + ((size_t)n * 512 + jg * 16 + d) * 16 + co);
            bf16x8 af = __builtin_bit_cast(bf16x8, a4);
            const int byteoff = (sp * 64 + g * 16) ^ ((d & 7) << 4);
            #pragma unroll
            for (int u = 0; u < 2; ++u) {
                unsigned av = arn_s[u][d][nl];
                float s = jl ? bhi(av) : blo(av);
                uint4 p4 = *reinterpret_cast<const uint4*>(
                    reinterpret_cast<const char*>(&pu_s8[h][u][d][0]) + byteoff);
                uint4 bb;
                bb.x = cvtpk(blo(p4.x) * s, bhi(p4.x) * s);
                bb.y = cvtpk(blo(p4.y) * s, bhi(p4.y) * s);
                bb.z = cvtpk(blo(p4.z) * s, bhi(p4.z) * s);
                bb.w = cvtpk(blo(p4.w) * s, bhi(p4.w) * s);
                bf16x8 bf = __builtin_bit_cast(bf16x8, bb);
                acc[u][sp & 1] = __builtin_amdgcn_mfma_f32_16x16x32_bf16(
                    af, bf, acc[u][sp & 1], 0, 0, 0);
            }
        }
    }

    __syncthreads();
    if (h == 1) {
        #pragma unroll
        for (int u = 0; u < 2; ++u) {
            f32x4 av = acc[u][0] + acc[u][1];
            #pragma unroll
            for (int i = 0; i < 4; ++i)
                red_s[jl][u][(g * 4 + i) * 16 + d] = av[i];
        }
    }
    __syncthreads();
    if (h == 0) {
        #pragma unroll
        for (int u = 0; u < 2; ++u) {
            f32x4 av = acc[u][0] + acc[u][1];
            const int bl = bl0 + u * 16 + d;
            const float inv = 1.0f / arsum[(size_t)bl * 32 + jg];
            #pragma unroll
            for (int i = 0; i < 4; ++i) {
                float vv = (av[i] + red_s[jl][u][(g * 4 + i) * 16 + d]) * inv;
                prep[((size_t)z * 512 + jg * 16 + g * 4 + i) * NBL + bl] = vv;
            }
        }
    }
}

// ---------------------------------------------------------------------------
// Kernel 4: BatchNorm (batch stats, biased var) + layout to [b, 512, 6, 6].
// ---------------------------------------------------------------------------
__global__ __launch_bounds__(256) void k_bn(
    const float* __restrict__ prep, const float* __restrict__ gamma,
    const float* __restrict__ beta, float* __restrict__ out_pose)
{
    const int tid = threadIdx.x;
    const int wid = tid >> 6, lane = tid & 63;
    const int ch  = blockIdx.x * 4 + wid;
    const float* p0 = prep + (size_t)ch * NBL;
    const float* p1 = p0 + 294912;

    float sum = 0.f, sq = 0.f;
    float v[9];
    #pragma unroll
    for (int k = 0; k < 9; ++k) {
        int i = lane + k * 64;
        float x = p0[i] + p1[i];
        v[k] = x;
        sum += x;
        sq  += x * x;
    }
    #pragma unroll
    for (int msk = 32; msk >= 1; msk >>= 1) {
        sum += __shfl_xor(sum, msk);
        sq  += __shfl_xor(sq, msk);
    }
    const float mean = sum * (1.f / 576.f);
    const float var  = sq * (1.f / 576.f) - mean * mean;
    const float inv  = rsqrtf(var + 1e-5f);
    const float sc   = gamma[ch] * inv;
    const float sh   = beta[ch] - mean * sc;
    #pragma unroll
    for (int k = 0; k < 9; ++k) {
        int i = lane + k * 64;
        int b = i / 36;
        int l = i - b * 36;
        out_pose[(size_t)b * 18432 + (size_t)ch * 36 + l] = v[k] * sc + sh;
    }
}

extern "C" void kernel_launch(void* const* d_in, const int* in_sizes, int n_in,
                              void* d_out, int out_size, void* d_ws, size_t ws_size,
                              hipStream_t stream)
{
    const float* a     = (const float*)d_in[0];
    const float* pose  = (const float*)d_in[1];
    const float* W1    = (const float*)d_in[2];
    const float* W2    = (const float*)d_in[3];
    const float* b2    = (const float*)d_in[4];
    const float* gamma = (const float*)d_in[5];
    const float* beta  = (const float*)d_in[6];
    float* out      = (float*)d_out;
    float* out_a    = out;              // [16, 32, 6, 6]
    float* out_pose = out + 18432;      // [16, 512, 6, 6]

    unsigned short* wsu = (unsigned short*)d_ws;
    unsigned short* W1b   = wsu + W1B_OFF;
    unsigned short* W2b   = wsu + W2B_OFF;
    unsigned short* pu16  = wsu + PU16_OFF;
    unsigned short* ar16  = wsu + AR16_OFF;
    float* wsf    = (float*)((char*)d_ws + FREG_BYTE);
    float* auf    = wsf + AU_F;
    float* arsump = wsf + ARSUMP_F;
    float* arsumv = wsf + ARSUM_F;
    float* prep   = wsf + PREP_F;

    hipLaunchKernelGGL(k_prep, dim3(1736), dim3(256), 0, stream,
                       W1, W2, a, pose, W1b, W2b, pu16, auf);
    hipLaunchKernelGGL(k_logit, dim3(36, 18), dim3(256), 0, stream,
                       W2b, pu16, b2, auf, ar16, arsump);
    hipLaunchKernelGGL(k_finish, dim3(144), dim3(256), 0, stream,
                       arsump, auf, arsumv, out_a);
    hipLaunchKernelGGL(k_pose, dim3(18, 16, 2), dim3(256), 0, stream,
                       W1b, pu16, ar16, arsumv, prep);
    hipLaunchKernelGGL(k_bn, dim3(128), dim3(256), 0, stream,
                       prep, gamma, beta, out_pose);
}